// Round 1
// baseline (252.298 us; speedup 1.0000x reference)
//
#include <hip/hip_runtime.h>

// Problem constants (x: (16,3,512,512) f32, PATCH=16, STRIDE=8, k=8)
#define BB     16
#define CH     3
#define HH     512
#define WW     512
#define PATCH_ 16
#define STRIDE_ 8
#define NH     63
#define NW     63
#define NN     3969          // NH*NW
#define FDIM   768           // CH*PATCH*PATCH
#define EDGES  31752         // NN*8

#define PATCHES_ELEMS  (BB * NN * FDIM)      // 48771072
#define POS_ELEMS      (BB * NN * 2)         // 127008
#define F4             (FDIM / 4)            // 192 float4 per (b,n)
#define TOTAL_G        (BB * NN * F4)        // 12192768 float4s

// ---------------------------------------------------------------------------
// Kernel 1: patches gather. One thread = one float4 of output (4 consecutive
// dj). Writes fully coalesced; reads are contiguous 64B runs per 4 lanes.
// ---------------------------------------------------------------------------
__global__ __launch_bounds__(256) void patches_kernel(const float* __restrict__ x,
                                                      float* __restrict__ out) {
    unsigned g = blockIdx.x * 256u + threadIdx.x;          // exact grid
    unsigned f4   = g % F4;
    unsigned rest = g / F4;
    unsigned n    = rest % NN;
    unsigned b    = rest / NN;

    unsigned f  = f4 << 2;              // feature index of first of 4
    unsigned c  = f >> 8;               // / 256
    unsigned di = (f >> 4) & 15;
    unsigned dj = f & 15;               // multiple of 4
    unsigned i  = n / NW;
    unsigned j  = n - i * NW;
    unsigned row = i * STRIDE_ + di;
    unsigned col = j * STRIDE_ + dj;

    const float4 v = *reinterpret_cast<const float4*>(
        x + ((size_t)((b * CH + c) * HH + row) * WW + col));
    *reinterpret_cast<float4*>(out + (size_t)g * 4) = v;
}

// ---------------------------------------------------------------------------
// Kernel 2: positions. One thread = one (b,n), writes float2 (i, j).
// ---------------------------------------------------------------------------
__global__ __launch_bounds__(256) void pos_kernel(float* __restrict__ out) {
    unsigned g = blockIdx.x * 256u + threadIdx.x;
    if (g >= BB * NN) return;
    unsigned n = g % NN;
    unsigned i = n / NW;
    unsigned j = n - i * NW;
    *reinterpret_cast<float2*>(out + (size_t)g * 2) =
        make_float2((float)i, (float)j);
}

// ---------------------------------------------------------------------------
// Kernel 3: 8-NN edges on the 63x63 grid. One thread per node; scan the
// clipped 5x5 window keeping the 9 smallest packed keys (d2<<12 | idx) —
// exactly reproduces jax.lax.top_k(-d2) ordering (ties -> lower index).
// Results broadcast to all 16 batches as float32.
// ---------------------------------------------------------------------------
__global__ __launch_bounds__(256) void edge_kernel(float* __restrict__ out) {
    unsigned n = blockIdx.x * 256u + threadIdx.x;
    if (n >= NN) return;
    int i = (int)(n / NW);
    int j = (int)(n - i * NW);

    unsigned best[9];
#pragma unroll
    for (int s = 0; s < 9; ++s) best[s] = 0xFFFFFFFFu;

    for (int di = -2; di <= 2; ++di) {
        int ni = i + di;
        if (ni < 0 || ni >= NH) continue;
        for (int dj = -2; dj <= 2; ++dj) {
            int nj = j + dj;
            if (nj < 0 || nj >= NW) continue;
            unsigned d2  = (unsigned)(di * di + dj * dj);
            unsigned key = (d2 << 12) | (unsigned)(ni * NW + nj);
#pragma unroll
            for (int s = 0; s < 9; ++s) {
                if (key < best[s]) { unsigned t = best[s]; best[s] = key; key = t; }
            }
        }
    }

    // best[0] == self (d2 = 0); targets are best[1..8]
    float tg[8];
#pragma unroll
    for (int t = 0; t < 8; ++t) tg[t] = (float)(best[t + 1] & 0xFFFu);

    float  src = (float)n;
    float4 s4  = make_float4(src, src, src, src);
    float4 t0  = make_float4(tg[0], tg[1], tg[2], tg[3]);
    float4 t1  = make_float4(tg[4], tg[5], tg[6], tg[7]);

    for (int b = 0; b < BB; ++b) {
        float* base = out + (size_t)b * 2 * EDGES;
        *reinterpret_cast<float4*>(base + (size_t)n * 8)         = s4;
        *reinterpret_cast<float4*>(base + (size_t)n * 8 + 4)     = s4;
        *reinterpret_cast<float4*>(base + EDGES + (size_t)n * 8)     = t0;
        *reinterpret_cast<float4*>(base + EDGES + (size_t)n * 8 + 4) = t1;
    }
}

extern "C" void kernel_launch(void* const* d_in, const int* in_sizes, int n_in,
                              void* d_out, int out_size, void* d_ws, size_t ws_size,
                              hipStream_t stream) {
    const float* x = (const float*)d_in[0];
    float* out     = (float*)d_out;

    float* patches = out;
    float* pos     = out + PATCHES_ELEMS;
    float* edge    = out + PATCHES_ELEMS + POS_ELEMS;

    patches_kernel<<<TOTAL_G / 256, 256, 0, stream>>>(x, patches);
    pos_kernel<<<(BB * NN + 255) / 256, 256, 0, stream>>>(pos);
    edge_kernel<<<(NN + 255) / 256, 256, 0, stream>>>(edge);
}